// Round 1
// baseline (359.610 us; speedup 1.0000x reference)
//
#include <hip/hip_runtime.h>
#include <math.h>

#define B_  2
#define N_  6890
#define BN  (B_ * N_)          // 13780

// ---------------------------------------------------------------------------
// prep: transpose v1,v2 [B,N,3] -> SoA planes [3][B*N]; gather triangle soups
//       tri1 = v1[faces], tri2 = v2[faces] as SoA [9][B*NF]
// ---------------------------------------------------------------------------
__global__ void prep_kernel(const float* __restrict__ v1, const float* __restrict__ v2,
                            const int* __restrict__ faces, int NF,
                            float* __restrict__ v1s, float* __restrict__ v2s,
                            float* __restrict__ tri1, float* __restrict__ tri2) {
    int tid = blockIdx.x * blockDim.x + threadIdx.x;
    if (tid < BN) {
        #pragma unroll
        for (int d = 0; d < 3; ++d) {
            v1s[d * BN + tid] = v1[tid * 3 + d];
            v2s[d * BN + tid] = v2[tid * 3 + d];
        }
    }
    int BF = B_ * NF;
    if (tid < BF) {
        int b = tid / NF, f = tid - b * NF;
        #pragma unroll
        for (int k = 0; k < 3; ++k) {
            int vid = faces[f * 3 + k];
            #pragma unroll
            for (int d = 0; d < 3; ++d) {
                tri1[(k * 3 + d) * BF + tid] = v1[(b * N_ + vid) * 3 + d];
                tri2[(k * 3 + d) * BF + tid] = v2[(b * N_ + vid) * 3 + d];
            }
        }
    }
}

// ---------------------------------------------------------------------------
// winding: one wave (64 lanes) per point. Lanes stride over triangles.
// Van Oosterom–Strackee solid angle, f32 per-triangle, f64 accumulation.
// Writes winding number (omega_sum / 4pi) per point.
// ---------------------------------------------------------------------------
__global__ void winding_kernel(const float* __restrict__ ps,   // [3][BN] point planes
                               const float* __restrict__ tri,  // [9][B*NF]
                               int NF,
                               float* __restrict__ wn) {
    int gt   = blockIdx.x * blockDim.x + threadIdx.x;
    int wave = gt >> 6;
    int lane = gt & 63;
    if (wave >= BN) return;
    int b = wave / N_;
    int BF = B_ * NF;

    float p0 = ps[wave], p1 = ps[BN + wave], p2 = ps[2 * BN + wave];
    const float* t = tri + b * NF;

    double acc = 0.0;
    for (int f = lane; f < NF; f += 64) {
        float ax = t[0 * BF + f] - p0, ay = t[1 * BF + f] - p1, az = t[2 * BF + f] - p2;
        float bx = t[3 * BF + f] - p0, by = t[4 * BF + f] - p1, bz = t[5 * BF + f] - p2;
        float cx = t[6 * BF + f] - p0, cy = t[7 * BF + f] - p1, cz = t[8 * BF + f] - p2;

        float la = sqrtf(ax * ax + ay * ay + az * az);
        float lb = sqrtf(bx * bx + by * by + bz * bz);
        float lc = sqrtf(cx * cx + cy * cy + cz * cz);

        // det = a . (b x c)
        float crx = by * cz - bz * cy;
        float cry = bz * cx - bx * cz;
        float crz = bx * cy - by * cx;
        float det = ax * crx + ay * cry + az * crz;

        float dab = ax * bx + ay * by + az * bz;
        float dbc = bx * cx + by * cy + bz * cz;
        float dca = cx * ax + cy * ay + cz * az;

        float denom = la * lb * lc + dab * lc + dbc * la + dca * lb;
        acc += (double)(2.0f * atan2f(det, denom));
    }
    #pragma unroll
    for (int off = 32; off > 0; off >>= 1)
        acc += __shfl_down(acc, off, 64);
    if (lane == 0)
        wn[wave] = (float)(acc * (1.0 / (4.0 * 3.14159265358979323846)));
}

// ---------------------------------------------------------------------------
// rowmin: one wave per x-point; lanes stride over y-points; min squared dist.
// ---------------------------------------------------------------------------
__global__ void rowmin_kernel(const float* __restrict__ xs,  // [3][BN]
                              const float* __restrict__ ys,  // [3][BN]
                              float* __restrict__ rmin) {
    int gt   = blockIdx.x * blockDim.x + threadIdx.x;
    int wave = gt >> 6;
    int lane = gt & 63;
    if (wave >= BN) return;
    int b = wave / N_;

    float p0 = xs[wave], p1 = xs[BN + wave], p2 = xs[2 * BN + wave];
    const float* y0 = ys + b * N_;
    const float* y1 = ys + BN + b * N_;
    const float* y2 = ys + 2 * BN + b * N_;

    float m = 3.4e38f;
    for (int j = lane; j < N_; j += 64) {
        float dx = y0[j] - p0;
        float dy = y1[j] - p1;
        float dz = y2[j] - p2;
        float d = dx * dx + dy * dy + dz * dz;
        m = fminf(m, d);
    }
    #pragma unroll
    for (int off = 32; off > 0; off >>= 1)
        m = fminf(m, __shfl_down(m, off, 64));
    if (lane == 0) rmin[wave] = m;
}

// ---------------------------------------------------------------------------
// finalize: one block per batch. Reduce global min + masked max/mean for both
// directions. out is [5][B] flat.
// ---------------------------------------------------------------------------
__global__ void finalize_kernel(const float* __restrict__ rmin1, const float* __restrict__ rmin2,
                                const float* __restrict__ wn1,   const float* __restrict__ wn2,
                                float* __restrict__ out) {
    int b   = blockIdx.x;
    int tid = threadIdx.x;

    float  gmin = 3.4e38f;
    float  mx1 = -1.0f, mx2 = -1.0f;
    double sum1 = 0.0,  sum2 = 0.0;
    int    c1 = 0,      c2 = 0;

    for (int i = tid; i < N_; i += blockDim.x) {
        float d1 = sqrtf(rmin1[b * N_ + i]);
        gmin = fminf(gmin, d1);
        if (wn1[b * N_ + i] >= 0.99f) { ++c1; sum1 += (double)d1; mx1 = fmaxf(mx1, d1); }
        float d2 = sqrtf(rmin2[b * N_ + i]);
        if (wn2[b * N_ + i] >= 0.99f) { ++c2; sum2 += (double)d2; mx2 = fmaxf(mx2, d2); }
    }

    __shared__ float  sf[256];
    __shared__ double sd[256];
    __shared__ int    si[256];

    float r_gmin, r_mx1, r_mx2;
    double r_s1, r_s2;
    int r_c1, r_c2;

#define REDUCE_F(val, OP, res)                                                  \
    sf[tid] = (val); __syncthreads();                                           \
    for (int s = 128; s > 0; s >>= 1) {                                         \
        if (tid < s) sf[tid] = OP(sf[tid], sf[tid + s]);                        \
        __syncthreads();                                                        \
    }                                                                           \
    res = sf[0]; __syncthreads();

#define REDUCE_D(val, res)                                                      \
    sd[tid] = (val); __syncthreads();                                           \
    for (int s = 128; s > 0; s >>= 1) {                                         \
        if (tid < s) sd[tid] = sd[tid] + sd[tid + s];                           \
        __syncthreads();                                                        \
    }                                                                           \
    res = sd[0]; __syncthreads();

#define REDUCE_I(val, res)                                                      \
    si[tid] = (val); __syncthreads();                                           \
    for (int s = 128; s > 0; s >>= 1) {                                         \
        if (tid < s) si[tid] = si[tid] + si[tid + s];                           \
        __syncthreads();                                                        \
    }                                                                           \
    res = si[0]; __syncthreads();

    REDUCE_F(gmin, fminf, r_gmin)
    REDUCE_F(mx1,  fmaxf, r_mx1)
    REDUCE_F(mx2,  fmaxf, r_mx2)
    REDUCE_D(sum1, r_s1)
    REDUCE_D(sum2, r_s2)
    REDUCE_I(c1,   r_c1)
    REDUCE_I(c2,   r_c2)

    if (tid == 0) {
        out[0 * B_ + b] = r_gmin;
        out[1 * B_ + b] = (r_c1 > 0) ? r_mx1 : 0.0f;
        out[2 * B_ + b] = (r_c1 > 0) ? (float)(r_s1 / (double)r_c1) : 0.0f;
        out[3 * B_ + b] = (r_c2 > 0) ? r_mx2 : 0.0f;
        out[4 * B_ + b] = (r_c2 > 0) ? (float)(r_s2 / (double)r_c2) : 0.0f;
    }
}

extern "C" void kernel_launch(void* const* d_in, const int* in_sizes, int n_in,
                              void* d_out, int out_size, void* d_ws, size_t ws_size,
                              hipStream_t stream) {
    const float* v1    = (const float*)d_in[0];
    const float* v2    = (const float*)d_in[1];
    const int*   faces = (const int*)d_in[2];
    int NF = in_sizes[2] / 3;          // 2000
    int BF = B_ * NF;

    float* w    = (float*)d_ws;
    float* v1s  = w;                   // 3*BN
    float* v2s  = v1s + 3 * BN;        // 3*BN
    float* tri1 = v2s + 3 * BN;        // 9*BF
    float* tri2 = tri1 + 9 * BF;       // 9*BF
    float* wn1  = tri2 + 9 * BF;       // BN
    float* wn2  = wn1 + BN;            // BN
    float* rm1  = wn2 + BN;            // BN
    float* rm2  = rm1 + BN;            // BN  (total ~840 KB)

    float* out = (float*)d_out;

    int prep_blocks = (BN + 255) / 256;
    prep_kernel<<<prep_blocks, 256, 0, stream>>>(v1, v2, faces, NF, v1s, v2s, tri1, tri2);

    int wave_blocks = (BN * 64 + 255) / 256;   // 3445
    // interior_v1 = winding(points=v1, tris from v2)
    winding_kernel<<<wave_blocks, 256, 0, stream>>>(v1s, tri2, NF, wn1);
    // interior_v2 = winding(points=v2, tris from v1)
    winding_kernel<<<wave_blocks, 256, 0, stream>>>(v2s, tri1, NF, wn2);

    // row_min: per v1 point min over v2 ; col_min: per v2 point min over v1
    rowmin_kernel<<<wave_blocks, 256, 0, stream>>>(v1s, v2s, rm1);
    rowmin_kernel<<<wave_blocks, 256, 0, stream>>>(v2s, v1s, rm2);

    finalize_kernel<<<B_, 256, 0, stream>>>(rm1, rm2, wn1, wn2, out);
}

// Round 2
// 217.565 us; speedup vs baseline: 1.6529x; 1.6529x over previous
//
#include <hip/hip_runtime.h>
#include <math.h>

#define B_    2
#define N_    6890
#define BN    (B_ * N_)            // 13780
#define NF_   2000
#define NFP_  2048                 // padded faces (32 iters * 64 lanes)
#define BFP_  (B_ * NFP_)          // 4096
#define P_    7168                 // padded N (28 * 256)

// ---------------------------------------------------------------------------
// fast atan2: octant reduction + Cephes poly on [0, tan(pi/8)].
// abs error ~3e-7 rad. Handles (0, +x)=0, (0,-x)=pi, signs like np.arctan2.
// ---------------------------------------------------------------------------
__device__ __forceinline__ float fast_atan2f(float y, float x) {
    float ax = __builtin_fabsf(x);
    float ay = __builtin_fabsf(y);
    float mx = fmaxf(ax, ay);
    float mn = fminf(ax, ay);
    float a  = mn * __builtin_amdgcn_rcpf(mx);        // [0,1]
    // reduce to |t| <= tan(pi/8): atan(a) = pi/4 + atan((a-1)/(a+1)) for a>tan(pi/8)
    bool  big = a > 0.4142135624f;
    float num = big ? (a - 1.0f) : a;
    float den = big ? (a + 1.0f) : 1.0f;
    float t   = num * __builtin_amdgcn_rcpf(den);
    float z   = t * t;
    float p   = fmaf(fmaf(fmaf(8.05374449538e-2f, z, -1.38776856032e-1f), z,
                          1.99777106478e-1f), z, -3.33329491539e-1f);
    float r   = fmaf(p * z, t, t);                     // atan(t)
    if (big)      r += 0.7853981634f;
    if (ay > ax)  r  = 1.5707963268f - r;
    if (x < 0.0f) r  = 3.1415926536f - r;
    return copysignf(r, y);
}

// ---------------------------------------------------------------------------
// prep: transpose clouds into padded SoA planes [3][B][P_] (pad = 1e19 so
// squared distances to pads are huge-but-finite); gather triangle soups into
// SoA [9][B][NFP_] (pad faces = all-ones vertices -> solid angle exactly 0).
// ---------------------------------------------------------------------------
__global__ void prep_kernel(const float* __restrict__ v1, const float* __restrict__ v2,
                            const int* __restrict__ faces,
                            float* __restrict__ v1s, float* __restrict__ v2s,
                            float* __restrict__ tri1, float* __restrict__ tri2) {
    int tid = blockIdx.x * 256 + threadIdx.x;
    if (tid < B_ * P_) {
        int b = tid / P_, n = tid - b * P_;
        if (n < N_) {
            #pragma unroll
            for (int d = 0; d < 3; ++d) {
                v1s[(d * B_ + b) * P_ + n] = v1[(b * N_ + n) * 3 + d];
                v2s[(d * B_ + b) * P_ + n] = v2[(b * N_ + n) * 3 + d];
            }
        } else {
            #pragma unroll
            for (int d = 0; d < 3; ++d) {
                v1s[(d * B_ + b) * P_ + n] = 1e19f;
                v2s[(d * B_ + b) * P_ + n] = 1e19f;
            }
        }
    }
    if (tid < B_ * NFP_) {
        int b = tid >> 11, f = tid & (NFP_ - 1);
        if (f < NF_) {
            #pragma unroll
            for (int k = 0; k < 3; ++k) {
                int vid = faces[f * 3 + k];
                #pragma unroll
                for (int d = 0; d < 3; ++d) {
                    tri1[(k * 3 + d) * BFP_ + tid] = v1[(b * N_ + vid) * 3 + d];
                    tri2[(k * 3 + d) * BFP_ + tid] = v2[(b * N_ + vid) * 3 + d];
                }
            }
        } else {
            #pragma unroll
            for (int e = 0; e < 9; ++e) {
                tri1[e * BFP_ + tid] = 1.0f;
                tri2[e * BFP_ + tid] = 1.0f;
            }
        }
    }
}

// ---------------------------------------------------------------------------
// winding (both directions in one launch): wave w < BN -> points v1 vs tri2
// (wn1); w >= BN -> points v2 vs tri1 (wn2). One wave per point, lanes stride
// triangles; exactly 32 iterations (NFP_/64). f64 accumulate + shfl reduce.
// ---------------------------------------------------------------------------
__global__ __launch_bounds__(256) void winding_kernel(
        const float* __restrict__ v1s, const float* __restrict__ v2s,
        const float* __restrict__ tri1, const float* __restrict__ tri2,
        float* __restrict__ wn1, float* __restrict__ wn2) {
    int gt   = blockIdx.x * 256 + threadIdx.x;
    int w    = gt >> 6;
    int lane = gt & 63;
    bool dir = (w >= BN);
    int  i   = dir ? (w - BN) : w;
    const float* ps  = dir ? v2s : v1s;
    const float* tri = dir ? tri1 : tri2;
    float*       wn  = dir ? wn2  : wn1;

    int b = i / N_, n = i - b * N_;
    float p0 = ps[(0 * B_ + b) * P_ + n];
    float p1 = ps[(1 * B_ + b) * P_ + n];
    float p2 = ps[(2 * B_ + b) * P_ + n];
    const float* t = tri + b * NFP_;

    double acc = 0.0;
    #pragma unroll 2
    for (int f = lane; f < NFP_; f += 64) {
        float ax = t[0 * BFP_ + f] - p0, ay = t[1 * BFP_ + f] - p1, az = t[2 * BFP_ + f] - p2;
        float bx = t[3 * BFP_ + f] - p0, by = t[4 * BFP_ + f] - p1, bz = t[5 * BFP_ + f] - p2;
        float cx = t[6 * BFP_ + f] - p0, cy = t[7 * BFP_ + f] - p1, cz = t[8 * BFP_ + f] - p2;

        float la = __builtin_amdgcn_sqrtf(fmaf(ax, ax, fmaf(ay, ay, az * az)));
        float lb = __builtin_amdgcn_sqrtf(fmaf(bx, bx, fmaf(by, by, bz * bz)));
        float lc = __builtin_amdgcn_sqrtf(fmaf(cx, cx, fmaf(cy, cy, cz * cz)));

        float crx = by * cz - bz * cy;
        float cry = bz * cx - bx * cz;
        float crz = bx * cy - by * cx;
        float det = fmaf(ax, crx, fmaf(ay, cry, az * crz));

        float dab = fmaf(ax, bx, fmaf(ay, by, az * bz));
        float dbc = fmaf(bx, cx, fmaf(by, cy, bz * cz));
        float dca = fmaf(cx, ax, fmaf(cy, ay, cz * az));

        float denom = fmaf(dab, lc, la * lb * lc);
        denom = fmaf(dbc, la, denom);
        denom = fmaf(dca, lb, denom);

        acc += (double)fast_atan2f(det, denom);
    }
    #pragma unroll
    for (int off = 32; off > 0; off >>= 1)
        acc += __shfl_down(acc, off, 64);
    if (lane == 0)
        wn[i] = (float)(acc * (1.0 / (2.0 * 3.14159265358979323846)));
}

// ---------------------------------------------------------------------------
// rowmin (both directions): wave w < BN -> v1 point vs v2 cloud (rm1);
// w >= BN -> v2 point vs v1 cloud (rm2). float4 loads, min squared dist.
// ---------------------------------------------------------------------------
__global__ __launch_bounds__(256) void rowmin_kernel(
        const float* __restrict__ v1s, const float* __restrict__ v2s,
        float* __restrict__ rm1, float* __restrict__ rm2) {
    int gt   = blockIdx.x * 256 + threadIdx.x;
    int w    = gt >> 6;
    int lane = gt & 63;
    bool dir = (w >= BN);
    int  i   = dir ? (w - BN) : w;
    const float* xs = dir ? v2s : v1s;
    const float* ys = dir ? v1s : v2s;
    float*       rm = dir ? rm2 : rm1;

    int b = i / N_, n = i - b * N_;
    float p0 = xs[(0 * B_ + b) * P_ + n];
    float p1 = xs[(1 * B_ + b) * P_ + n];
    float p2 = xs[(2 * B_ + b) * P_ + n];
    const float* y0 = ys + (0 * B_ + b) * P_;
    const float* y1 = ys + (1 * B_ + b) * P_;
    const float* y2 = ys + (2 * B_ + b) * P_;

    float m = 3.4e38f;
    for (int it = 0; it < P_ / 256; ++it) {
        int j = it * 256 + lane * 4;
        float4 X = *(const float4*)(y0 + j);
        float4 Y = *(const float4*)(y1 + j);
        float4 Z = *(const float4*)(y2 + j);
        #define DO(c) { float dx = X.c - p0, dy = Y.c - p1, dz = Z.c - p2; \
                        m = fminf(m, fmaf(dx, dx, fmaf(dy, dy, dz * dz))); }
        DO(x) DO(y) DO(z) DO(w)
        #undef DO
    }
    #pragma unroll
    for (int off = 32; off > 0; off >>= 1)
        m = fminf(m, __shfl_down(m, off, 64));
    if (lane == 0) rm[i] = m;
}

// ---------------------------------------------------------------------------
// finalize: one block per batch; global min + masked max/mean both directions.
// out is [5][B] flat. rm holds squared distances.
// ---------------------------------------------------------------------------
__global__ void finalize_kernel(const float* __restrict__ rmin1, const float* __restrict__ rmin2,
                                const float* __restrict__ wn1,   const float* __restrict__ wn2,
                                float* __restrict__ out) {
    int b   = blockIdx.x;
    int tid = threadIdx.x;

    float  gmin = 3.4e38f;
    float  mx1 = -1.0f, mx2 = -1.0f;
    double sum1 = 0.0,  sum2 = 0.0;
    int    c1 = 0,      c2 = 0;

    for (int i = tid; i < N_; i += blockDim.x) {
        float d1 = sqrtf(rmin1[b * N_ + i]);
        gmin = fminf(gmin, d1);
        if (wn1[b * N_ + i] >= 0.99f) { ++c1; sum1 += (double)d1; mx1 = fmaxf(mx1, d1); }
        float d2 = sqrtf(rmin2[b * N_ + i]);
        if (wn2[b * N_ + i] >= 0.99f) { ++c2; sum2 += (double)d2; mx2 = fmaxf(mx2, d2); }
    }

    __shared__ float  sf[256];
    __shared__ double sd[256];
    __shared__ int    si[256];

    float r_gmin, r_mx1, r_mx2;
    double r_s1, r_s2;
    int r_c1, r_c2;

#define REDUCE_F(val, OP, res)                                                  \
    sf[tid] = (val); __syncthreads();                                           \
    for (int s = 128; s > 0; s >>= 1) {                                         \
        if (tid < s) sf[tid] = OP(sf[tid], sf[tid + s]);                        \
        __syncthreads();                                                        \
    }                                                                           \
    res = sf[0]; __syncthreads();

#define REDUCE_D(val, res)                                                      \
    sd[tid] = (val); __syncthreads();                                           \
    for (int s = 128; s > 0; s >>= 1) {                                         \
        if (tid < s) sd[tid] = sd[tid] + sd[tid + s];                           \
        __syncthreads();                                                        \
    }                                                                           \
    res = sd[0]; __syncthreads();

#define REDUCE_I(val, res)                                                      \
    si[tid] = (val); __syncthreads();                                           \
    for (int s = 128; s > 0; s >>= 1) {                                         \
        if (tid < s) si[tid] = si[tid] + si[tid + s];                           \
        __syncthreads();                                                        \
    }                                                                           \
    res = si[0]; __syncthreads();

    REDUCE_F(gmin, fminf, r_gmin)
    REDUCE_F(mx1,  fmaxf, r_mx1)
    REDUCE_F(mx2,  fmaxf, r_mx2)
    REDUCE_D(sum1, r_s1)
    REDUCE_D(sum2, r_s2)
    REDUCE_I(c1,   r_c1)
    REDUCE_I(c2,   r_c2)

    if (tid == 0) {
        out[0 * B_ + b] = r_gmin;
        out[1 * B_ + b] = (r_c1 > 0) ? r_mx1 : 0.0f;
        out[2 * B_ + b] = (r_c1 > 0) ? (float)(r_s1 / (double)r_c1) : 0.0f;
        out[3 * B_ + b] = (r_c2 > 0) ? r_mx2 : 0.0f;
        out[4 * B_ + b] = (r_c2 > 0) ? (float)(r_s2 / (double)r_c2) : 0.0f;
    }
}

extern "C" void kernel_launch(void* const* d_in, const int* in_sizes, int n_in,
                              void* d_out, int out_size, void* d_ws, size_t ws_size,
                              hipStream_t stream) {
    const float* v1    = (const float*)d_in[0];
    const float* v2    = (const float*)d_in[1];
    const int*   faces = (const int*)d_in[2];

    float* w    = (float*)d_ws;
    float* v1s  = w;                     // 3*B_*P_   = 43008
    float* v2s  = v1s + 3 * B_ * P_;     // 43008
    float* tri1 = v2s + 3 * B_ * P_;     // 9*BFP_    = 36864
    float* tri2 = tri1 + 9 * BFP_;       // 36864
    float* wn1  = tri2 + 9 * BFP_;       // BN
    float* wn2  = wn1 + BN;
    float* rm1  = wn2 + BN;
    float* rm2  = rm1 + BN;              // total ~860 KB

    float* out = (float*)d_out;

    prep_kernel<<<(B_ * P_ + 255) / 256, 256, 0, stream>>>(v1, v2, faces, v1s, v2s, tri1, tri2);

    int wave_blocks = (2 * BN * 64) / 256;   // 6890, dir boundary block-aligned
    winding_kernel<<<wave_blocks, 256, 0, stream>>>(v1s, v2s, tri1, tri2, wn1, wn2);
    rowmin_kernel<<<wave_blocks, 256, 0, stream>>>(v1s, v2s, rm1, rm2);

    finalize_kernel<<<B_, 256, 0, stream>>>(rm1, rm2, wn1, wn2, out);
}

// Round 3
// 192.307 us; speedup vs baseline: 1.8700x; 1.1313x over previous
//
#include <hip/hip_runtime.h>
#include <math.h>

#define B_      2
#define N_      6890
#define BN      (B_ * N_)          // 13780
#define NF_     2000
#define NFP_    2048               // padded triangles
#define P_      7168               // padded N for rowmin planes (28*256)
#define NP4_    6912               // padded N for winding point float4s (27*256)
#define CHUNKS_ 16
#define CTRI_   (NFP_ / CHUNKS_)   // 128 triangles per chunk

// ---------------------------------------------------------------------------
// atan2(y,x)/(2*pi): single-rcp octant reduction, scale folded into poly.
// abs error ~5e-8 (scaled). Sign/quadrant semantics match np.arctan2.
// ---------------------------------------------------------------------------
__device__ __forceinline__ float atan2_o2pi(float y, float x) {
    float ax = __builtin_fabsf(x);
    float ay = __builtin_fabsf(y);
    float mx = fmaxf(ax, ay);
    float mn = fminf(ax, ay);
    bool  big = mn > 0.41421356f * mx;              // a > tan(pi/8)
    float num = big ? (mn - mx) : mn;               // (a-1)/(a+1) pre-division
    float den = big ? (mn + mx) : mx;
    float t   = num * __builtin_amdgcn_rcpf(den);
    float z   = t * t;
    float p   = fmaf(fmaf(fmaf(1.2817932e-2f, z, -2.2087019e-2f), z,
                          3.1795514e-2f), z, -5.3051037e-2f);   // coeffs / 2pi
    float r   = t * fmaf(z, p, 0.15915494309f);     // atan(t)/2pi
    if (big)      r += 0.125f;                      // + (pi/4)/2pi
    if (ay > ax)  r  = 0.25f - r;                   // pi/2 - .
    if (x < 0.0f) r  = 0.5f  - r;                   // pi - .
    return copysignf(r, y);
}

// ---------------------------------------------------------------------------
// prep:
//  job A: plane SoA [3][B][P_] for rowmin (pad 1e19)
//  job B: point float4 (x,y,z,|p|^2) [B][NP4_] for winding (pad zeros)
//  job C: per-triangle 20-float table for both soups:
//         [A(3) B(3) C(3) S(3) det0 na nb nc qab qbc qca pad]
//         pad triangles = (1,1,1)x3 -> S=0, det0=0 -> contribution exactly 0.
// ---------------------------------------------------------------------------
__global__ void prep_kernel(const float* __restrict__ v1, const float* __restrict__ v2,
                            const int* __restrict__ faces,
                            float* __restrict__ v1s, float* __restrict__ v2s,
                            float4* __restrict__ pw1, float4* __restrict__ pw2,
                            float* __restrict__ tbl1, float* __restrict__ tbl2) {
    int tid = blockIdx.x * 256 + threadIdx.x;

    if (tid < B_ * P_) {                       // job A
        int b = tid / P_, n = tid - b * P_;
        if (n < N_) {
            #pragma unroll
            for (int d = 0; d < 3; ++d) {
                v1s[(d * B_ + b) * P_ + n] = v1[(b * N_ + n) * 3 + d];
                v2s[(d * B_ + b) * P_ + n] = v2[(b * N_ + n) * 3 + d];
            }
        } else {
            #pragma unroll
            for (int d = 0; d < 3; ++d) {
                v1s[(d * B_ + b) * P_ + n] = 1e19f;
                v2s[(d * B_ + b) * P_ + n] = 1e19f;
            }
        }
    }

    if (tid < B_ * NP4_) {                     // job B
        int b = tid / NP4_, n = tid - b * NP4_;
        float4 q1 = make_float4(0.f, 0.f, 0.f, 0.f);
        float4 q2 = q1;
        if (n < N_) {
            float x1 = v1[(b * N_ + n) * 3 + 0], y1 = v1[(b * N_ + n) * 3 + 1], z1 = v1[(b * N_ + n) * 3 + 2];
            float x2 = v2[(b * N_ + n) * 3 + 0], y2 = v2[(b * N_ + n) * 3 + 1], z2 = v2[(b * N_ + n) * 3 + 2];
            q1 = make_float4(x1, y1, z1, fmaf(x1, x1, fmaf(y1, y1, z1 * z1)));
            q2 = make_float4(x2, y2, z2, fmaf(x2, x2, fmaf(y2, y2, z2 * z2)));
        }
        pw1[tid] = q1;
        pw2[tid] = q2;
    }

    if (tid < 2 * B_ * NFP_) {                 // job C
        int src = tid >> 12;                   // 0: table from v1, 1: from v2
        int rr  = tid & (B_ * NFP_ - 1);
        int b   = rr >> 11;
        int f   = rr & (NFP_ - 1);
        const float* V = src ? v2 : v1;
        float Ax=1.f, Ay=1.f, Az=1.f, Bx=1.f, By=1.f, Bz=1.f, Cx=1.f, Cy=1.f, Cz=1.f;
        if (f < NF_) {
            int i0 = faces[f * 3 + 0], i1 = faces[f * 3 + 1], i2 = faces[f * 3 + 2];
            Ax = V[(b * N_ + i0) * 3 + 0]; Ay = V[(b * N_ + i0) * 3 + 1]; Az = V[(b * N_ + i0) * 3 + 2];
            Bx = V[(b * N_ + i1) * 3 + 0]; By = V[(b * N_ + i1) * 3 + 1]; Bz = V[(b * N_ + i1) * 3 + 2];
            Cx = V[(b * N_ + i2) * 3 + 0]; Cy = V[(b * N_ + i2) * 3 + 1]; Cz = V[(b * N_ + i2) * 3 + 2];
        }
        // S = AxB + BxC + CxA
        float Sx = (Ay*Bz - Az*By) + (By*Cz - Bz*Cy) + (Cy*Az - Cz*Ay);
        float Sy = (Az*Bx - Ax*Bz) + (Bz*Cx - Bx*Cz) + (Cz*Ax - Cx*Az);
        float Sz = (Ax*By - Ay*Bx) + (Bx*Cy - By*Cx) + (Cx*Ay - Cy*Ax);
        float det0 = Ax*(By*Cz - Bz*Cy) + Ay*(Bz*Cx - Bx*Cz) + Az*(Bx*Cy - By*Cx);
        float na = Ax*Ax + Ay*Ay + Az*Az;
        float nb = Bx*Bx + By*By + Bz*Bz;
        float nc = Cx*Cx + Cy*Cy + Cz*Cz;
        float qab = Ax*Bx + Ay*By + Az*Bz;
        float qbc = Bx*Cx + By*Cy + Bz*Cz;
        float qca = Cx*Ax + Cy*Ay + Cz*Az;
        float* o = (src ? tbl2 : tbl1) + ((b << 11) + f) * 20;
        o[0]=Ax; o[1]=Ay; o[2]=Az; o[3]=Bx; o[4]=By; o[5]=Bz; o[6]=Cx; o[7]=Cy; o[8]=Cz;
        o[9]=Sx; o[10]=Sy; o[11]=Sz; o[12]=det0; o[13]=na; o[14]=nb; o[15]=nc;
        o[16]=qab; o[17]=qbc; o[18]=qca; o[19]=0.f;
    }
}

// ---------------------------------------------------------------------------
// winding: block = 256 points (4 waves) x one 128-triangle chunk staged in
// LDS. Lane owns a point; triangle constants broadcast via ds_read_b128.
// grid: ((dir*2+b)*27 + pg)*16 + c  -> 1728 blocks.
// ---------------------------------------------------------------------------
__global__ __launch_bounds__(256) void winding_kernel(
        const float4* __restrict__ pw1, const float4* __restrict__ pw2,
        const float* __restrict__ tbl1, const float* __restrict__ tbl2,
        float* __restrict__ part) {
    __shared__ float T[CTRI_ * 20];            // 10 KB
    int bid = blockIdx.x;
    int c   = bid & (CHUNKS_ - 1);
    int r   = bid >> 4;
    int pg  = r % 27;
    int db  = r / 27;                          // dir*2 + b
    int b   = db & 1, dir = db >> 1;

    const float4* pw  = dir ? pw2 : pw1;       // dir0: points v1 vs tris(v2)
    const float*  tbl = dir ? tbl1 : tbl2;

    const float* srcp = tbl + (b * NFP_ + c * CTRI_) * 20;
    #pragma unroll
    for (int k = 0; k < (CTRI_ * 20) / 256; ++k)
        T[k * 256 + threadIdx.x] = srcp[k * 256 + threadIdx.x];
    __syncthreads();

    int n = pg * 256 + threadIdx.x;            // < NP4_
    float4 P = pw[b * NP4_ + n];
    float p0 = P.x, p1 = P.y, p2 = P.z, pp = P.w;

    double acc = 0.0;
    #pragma unroll 2
    for (int f = 0; f < CTRI_; ++f) {
        const float4* t = (const float4*)(T + f * 20);
        float4 u0 = t[0], u1 = t[1], u2 = t[2], u3 = t[3], u4 = t[4];
        // u0=(Ax,Ay,Az,Bx) u1=(By,Bz,Cx,Cy) u2=(Cz,Sx,Sy,Sz)
        // u3=(det0,na,nb,nc) u4=(qab,qbc,qca,-)
        float dAp = fmaf(u0.x, p0, fmaf(u0.y, p1, u0.z * p2));
        float dBp = fmaf(u0.w, p0, fmaf(u1.x, p1, u1.y * p2));
        float dCp = fmaf(u1.z, p0, fmaf(u1.w, p1, u2.x * p2));
        float dSp = fmaf(u2.y, p0, fmaf(u2.z, p1, u2.w * p2));
        float det = u3.x - dSp;
        float la2 = fmaxf(fmaf(-2.f, dAp, u3.y + pp), 0.f);
        float lb2 = fmaxf(fmaf(-2.f, dBp, u3.z + pp), 0.f);
        float lc2 = fmaxf(fmaf(-2.f, dCp, u3.w + pp), 0.f);
        float la = __builtin_amdgcn_sqrtf(la2);
        float lb = __builtin_amdgcn_sqrtf(lb2);
        float lc = __builtin_amdgcn_sqrtf(lc2);
        float dab = (u4.x + pp) - (dAp + dBp);
        float dbc = (u4.y + pp) - (dBp + dCp);
        float dca = (u4.z + pp) - (dCp + dAp);
        float denom = la * lb * lc;
        denom = fmaf(dab, lc, denom);
        denom = fmaf(dbc, la, denom);
        denom = fmaf(dca, lb, denom);
        acc += (double)atan2_o2pi(det, denom);
    }
    part[((dir * 2 + b) * CHUNKS_ + c) * NP4_ + n] = (float)acc;
}

// ---------------------------------------------------------------------------
// rowmin (both directions, unchanged structure): wave=point, lanes stride the
// opposite padded cloud planes with float4 loads; min squared distance.
// ---------------------------------------------------------------------------
__global__ __launch_bounds__(256) void rowmin_kernel(
        const float* __restrict__ v1s, const float* __restrict__ v2s,
        float* __restrict__ rm1, float* __restrict__ rm2) {
    int gt   = blockIdx.x * 256 + threadIdx.x;
    int w    = gt >> 6;
    int lane = gt & 63;
    bool dir = (w >= BN);
    int  i   = dir ? (w - BN) : w;
    const float* xs = dir ? v2s : v1s;
    const float* ys = dir ? v1s : v2s;
    float*       rm = dir ? rm2 : rm1;

    int b = i / N_, n = i - b * N_;
    float p0 = xs[(0 * B_ + b) * P_ + n];
    float p1 = xs[(1 * B_ + b) * P_ + n];
    float p2 = xs[(2 * B_ + b) * P_ + n];
    const float* y0 = ys + (0 * B_ + b) * P_;
    const float* y1 = ys + (1 * B_ + b) * P_;
    const float* y2 = ys + (2 * B_ + b) * P_;

    float m = 3.4e38f;
    for (int it = 0; it < P_ / 256; ++it) {
        int j = it * 256 + lane * 4;
        float4 X = *(const float4*)(y0 + j);
        float4 Y = *(const float4*)(y1 + j);
        float4 Z = *(const float4*)(y2 + j);
        #define DO(c) { float dx = X.c - p0, dy = Y.c - p1, dz = Z.c - p2; \
                        m = fminf(m, fmaf(dx, dx, fmaf(dy, dy, dz * dz))); }
        DO(x) DO(y) DO(z) DO(w)
        #undef DO
    }
    #pragma unroll
    for (int off = 32; off > 0; off >>= 1)
        m = fminf(m, __shfl_down(m, off, 64));
    if (lane == 0) rm[i] = m;
}

// ---------------------------------------------------------------------------
// finalize: one block per batch; sums the 16 winding partials per point,
// then global min + masked max/mean for both directions. out = [5][B].
// ---------------------------------------------------------------------------
__global__ void finalize_kernel(const float* __restrict__ rmin1, const float* __restrict__ rmin2,
                                const float* __restrict__ part,
                                float* __restrict__ out) {
    int b   = blockIdx.x;
    int tid = threadIdx.x;

    float  gmin = 3.4e38f;
    float  mx1 = -1.0f, mx2 = -1.0f;
    double sum1 = 0.0,  sum2 = 0.0;
    int    c1 = 0,      c2 = 0;

    for (int i = tid; i < N_; i += blockDim.x) {
        float w1 = 0.f, w2 = 0.f;
        #pragma unroll
        for (int c = 0; c < CHUNKS_; ++c) {
            w1 += part[((0 * 2 + b) * CHUNKS_ + c) * NP4_ + i];
            w2 += part[((1 * 2 + b) * CHUNKS_ + c) * NP4_ + i];
        }
        float d1 = sqrtf(rmin1[b * N_ + i]);
        gmin = fminf(gmin, d1);
        if (w1 >= 0.99f) { ++c1; sum1 += (double)d1; mx1 = fmaxf(mx1, d1); }
        float d2 = sqrtf(rmin2[b * N_ + i]);
        if (w2 >= 0.99f) { ++c2; sum2 += (double)d2; mx2 = fmaxf(mx2, d2); }
    }

    __shared__ float  sf[256];
    __shared__ double sd[256];
    __shared__ int    si[256];

    float r_gmin, r_mx1, r_mx2;
    double r_s1, r_s2;
    int r_c1, r_c2;

#define REDUCE_F(val, OP, res)                                                  \
    sf[tid] = (val); __syncthreads();                                           \
    for (int s = 128; s > 0; s >>= 1) {                                         \
        if (tid < s) sf[tid] = OP(sf[tid], sf[tid + s]);                        \
        __syncthreads();                                                        \
    }                                                                           \
    res = sf[0]; __syncthreads();

#define REDUCE_D(val, res)                                                      \
    sd[tid] = (val); __syncthreads();                                           \
    for (int s = 128; s > 0; s >>= 1) {                                         \
        if (tid < s) sd[tid] = sd[tid] + sd[tid + s];                           \
        __syncthreads();                                                        \
    }                                                                           \
    res = sd[0]; __syncthreads();

#define REDUCE_I(val, res)                                                      \
    si[tid] = (val); __syncthreads();                                           \
    for (int s = 128; s > 0; s >>= 1) {                                         \
        if (tid < s) si[tid] = si[tid] + si[tid + s];                           \
        __syncthreads();                                                        \
    }                                                                           \
    res = si[0]; __syncthreads();

    REDUCE_F(gmin, fminf, r_gmin)
    REDUCE_F(mx1,  fmaxf, r_mx1)
    REDUCE_F(mx2,  fmaxf, r_mx2)
    REDUCE_D(sum1, r_s1)
    REDUCE_D(sum2, r_s2)
    REDUCE_I(c1,   r_c1)
    REDUCE_I(c2,   r_c2)

    if (tid == 0) {
        out[0 * B_ + b] = r_gmin;
        out[1 * B_ + b] = (r_c1 > 0) ? r_mx1 : 0.0f;
        out[2 * B_ + b] = (r_c1 > 0) ? (float)(r_s1 / (double)r_c1) : 0.0f;
        out[3 * B_ + b] = (r_c2 > 0) ? r_mx2 : 0.0f;
        out[4 * B_ + b] = (r_c2 > 0) ? (float)(r_s2 / (double)r_c2) : 0.0f;
    }
}

extern "C" void kernel_launch(void* const* d_in, const int* in_sizes, int n_in,
                              void* d_out, int out_size, void* d_ws, size_t ws_size,
                              hipStream_t stream) {
    const float* v1    = (const float*)d_in[0];
    const float* v2    = (const float*)d_in[1];
    const int*   faces = (const int*)d_in[2];

    float* w    = (float*)d_ws;
    float*  v1s  = w;                          // 3*B*P_      = 43008
    float*  v2s  = v1s + 3 * B_ * P_;          // 43008
    float4* pw1  = (float4*)(v2s + 3 * B_ * P_);   // B*NP4_*4 = 55296
    float4* pw2  = pw1 + B_ * NP4_;                // 55296
    float*  tbl1 = (float*)(pw2 + B_ * NP4_);      // B*NFP_*20 = 81920
    float*  tbl2 = tbl1 + B_ * NFP_ * 20;          // 81920
    float*  part = tbl2 + B_ * NFP_ * 20;          // 4*16*NP4_ = 442368
    float*  rm1  = part + 4 * CHUNKS_ * NP4_;      // 13780
    float*  rm2  = rm1 + BN;                       // 13780  (total ~3.3 MB)

    float* out = (float*)d_out;

    prep_kernel<<<(B_ * P_ + 255) / 256, 256, 0, stream>>>(
        v1, v2, faces, v1s, v2s, pw1, pw2, tbl1, tbl2);

    winding_kernel<<<2 * 2 * 27 * CHUNKS_, 256, 0, stream>>>(
        pw1, pw2, tbl1, tbl2, part);

    rowmin_kernel<<<(2 * BN * 64) / 256, 256, 0, stream>>>(v1s, v2s, rm1, rm2);

    finalize_kernel<<<B_, 256, 0, stream>>>(rm1, rm2, part, out);
}